// Round 2
// baseline (159.734 us; speedup 1.0000x reference)
//
#include <hip/hip_runtime.h>
#include <cstdint>

#define NB 4
#define ND 1024
#define NT 2048
#define NH 16
#define NE 64
#define GLEN 2240  // per-copy length of reversed global Toeplitz table (elements)
#define CAP 2312   // per-copy length of LDS table (elements)

typedef __bf16 bf16x8 __attribute__((ext_vector_type(8)));
typedef float f32x4 __attribute__((ext_vector_type(4)));
typedef unsigned short us8 __attribute__((ext_vector_type(8)));
typedef unsigned short us4 __attribute__((ext_vector_type(4)));

__device__ __forceinline__ unsigned short f2bf(float f) {
  unsigned u = __builtin_bit_cast(unsigned, f);
  return (unsigned short)((u + 0x7fffu + ((u >> 16) & 1u)) >> 16);  // RTNE
}

// async global->LDS, 16B per lane; LDS dest must be wave-uniform base + lane*16
__device__ __forceinline__ void gload16(const void* g, void* l) {
  __builtin_amdgcn_global_load_lds(
      (const __attribute__((address_space(1))) void*)(uintptr_t)g,
      (__attribute__((address_space(3))) void*)(uintptr_t)l, 16, 0, 0);
}

// ---------------------------------------------------------------- prep ------
__global__ void prep_kernel(const float* __restrict__ Wp, const float* __restrict__ Wo,
                            const float* __restrict__ tw,
                            unsigned short* __restrict__ WpB, unsigned short* __restrict__ WoB,
                            unsigned short* __restrict__ Gr8) {
  int idx = blockIdx.x * 256 + threadIdx.x;
  int stride = gridDim.x * 256;
  const int n4 = ND * ND / 4;
  for (int i = idx; i < n4; i += stride) {
    float4 v = ((const float4*)Wp)[i];
    us4 o = {f2bf(v.x), f2bf(v.y), f2bf(v.z), f2bf(v.w)};
    ((us4*)WpB)[i] = o;
  }
  for (int i = idx; i < n4; i += stride) {
    float4 v = ((const float4*)Wo)[i];
    us4 o = {f2bf(v.x), f2bf(v.y), f2bf(v.z), f2bf(v.w)};
    ((us4*)WoB)[i] = o;
  }
  for (int i = idx; i < NH * 8 * GLEN; i += stride) {
    int h = i / (8 * GLEN);
    int rem = i - h * 8 * GLEN;
    int r = rem / GLEN;
    int c = rem - r * GLEN;
    int src = c + r;
    Gr8[i] = (src <= NT - 1) ? f2bf(tw[h * NT + (NT - 1) - src]) : (unsigned short)0;
  }
}

// ------------------------------------------------------- transpose + cast ---
__global__ __launch_bounds__(256) void transpose_cast(const float* __restrict__ x,
                                                      unsigned short* __restrict__ xT) {
  __shared__ float tile[64][65];
  const int c = threadIdx.x & 15, r = threadIdx.x >> 4;
  const int t0 = blockIdx.x * 64, d0 = blockIdx.y * 64, b = blockIdx.z;
  const float* xb = x + (long)b * ND * NT;
#pragma unroll
  for (int k = 0; k < 4; ++k) {
    float4 v = *(const float4*)&xb[(long)(d0 + r + 16 * k) * NT + t0 + 4 * c];
    tile[r + 16 * k][4 * c + 0] = v.x;
    tile[r + 16 * k][4 * c + 1] = v.y;
    tile[r + 16 * k][4 * c + 2] = v.z;
    tile[r + 16 * k][4 * c + 3] = v.w;
  }
  __syncthreads();
  unsigned short* xTb = xT + (long)b * NT * ND;
#pragma unroll
  for (int k = 0; k < 4; ++k) {
    int t = r + 16 * k;
    us4 o = {f2bf(tile[4 * c + 0][t]), f2bf(tile[4 * c + 1][t]), f2bf(tile[4 * c + 2][t]),
             f2bf(tile[4 * c + 3][t])};
    *(us4*)&xTb[(long)(t0 + t) * ND + d0 + 4 * c] = o;
  }
}

// ----------------------------------------------------------- gemm_bt --------
// C[b][m][n] = sum_k A[m][k] * Bt[b][n][k] + bias[m]
// Pipelined (T2+T3+T4+T5): BM=128, BN=256, BK=64, 512 threads (8 waves 2Mx4N),
// grid 8x8x4 = 256 blocks = 1/CU, triple-buffered LDS, stage depth 2 K-tiles,
// counted s_waitcnt vmcnt(6) at tile head (never 0 in main loop), raw
// s_barrier, XOR-swizzled global source + swizzled ds_read (rule 21),
// s_setprio(1) around MFMA clusters.
template <bool OUT_BF16>
__global__ __launch_bounds__(512, 2) void gemm_bt(const unsigned short* __restrict__ A,
                                                  const unsigned short* __restrict__ Bt,
                                                  const float* __restrict__ bias,
                                                  void* __restrict__ Cb, long strideB,
                                                  long strideC) {
  const int N = 2048, K = 1024;
  __shared__ __align__(16) unsigned short As[3][128 * 64];  // 48 KiB
  __shared__ __align__(16) unsigned short Bs[3][256 * 64];  // 96 KiB
  const int tid = threadIdx.x;
  const int lane = tid & 63;
  const int wid = tid >> 6;
  const int wm = (wid & 1) * 64, wn = (wid >> 1) * 64;
  const int m0 = blockIdx.y * 128, n0 = blockIdx.x * 256;
  const unsigned short* Bb = Bt + (long)blockIdx.z * strideB;
  const int mlo = lane & 15, q = lane >> 4, m7 = mlo & 7;

  const int r0 = tid >> 3;                // 0..63
  const int xblk = (tid & 7) ^ (r0 & 7);  // inverse-swizzled source block
  const unsigned short* aSrc = A + (long)(m0 + r0) * K + xblk * 8;
  const unsigned short* bSrc = Bb + (long)(n0 + r0) * K + xblk * 8;

  auto stage0 = [&](int buf, int t) {  // A rows 0..127 + B rows 0..63  (3 loads)
    gload16(aSrc + t * 64, &As[buf][tid * 8]);
    gload16(aSrc + 64 * (long)K + t * 64, &As[buf][(512 + tid) * 8]);
    gload16(bSrc + t * 64, &Bs[buf][tid * 8]);
  };
  auto stage1 = [&](int buf, int t) {  // B rows 64..255  (3 loads)
    gload16(bSrc + 64 * (long)K + t * 64, &Bs[buf][(512 + tid) * 8]);
    gload16(bSrc + 128 * (long)K + t * 64, &Bs[buf][(1024 + tid) * 8]);
    gload16(bSrc + 192 * (long)K + t * 64, &Bs[buf][(1536 + tid) * 8]);
  };

  f32x4 acc[4][4] = {};
  stage0(0, 0);
  stage1(0, 0);
  stage0(1, 1);
  stage1(1, 1);

#pragma unroll
  for (int t = 0; t < 16; ++t) {
    const int buf = t % 3;
    if (t < 15)
      asm volatile("s_waitcnt vmcnt(6) lgkmcnt(0)" ::: "memory");
    else
      asm volatile("s_waitcnt vmcnt(0) lgkmcnt(0)" ::: "memory");
    __builtin_amdgcn_s_barrier();
#pragma unroll
    for (int ks = 0; ks < 2; ++ks) {
      bf16x8 av[4], bv[4];
      const int xb8 = ((4 * ks + q) ^ m7) * 8;
#pragma unroll
      for (int i = 0; i < 4; ++i) {
        av[i] = __builtin_bit_cast(bf16x8, *(const us8*)&As[buf][(wm + i * 16 + mlo) * 64 + xb8]);
        bv[i] = __builtin_bit_cast(bf16x8, *(const us8*)&Bs[buf][(wn + i * 16 + mlo) * 64 + xb8]);
      }
      if (t + 2 < 16) {
        if (ks == 0)
          stage0((t + 2) % 3, t + 2);
        else
          stage1((t + 2) % 3, t + 2);
      }
      __builtin_amdgcn_s_setprio(1);
#pragma unroll
      for (int i = 0; i < 4; ++i)
#pragma unroll
        for (int j = 0; j < 4; ++j)
          acc[i][j] = __builtin_amdgcn_mfma_f32_16x16x32_bf16(av[i], bv[j], acc[i][j], 0, 0, 0);
      __builtin_amdgcn_s_setprio(0);
    }
  }

  // epilogue: C/D layout col=lane&15, row=(lane>>4)*4+r
#pragma unroll
  for (int i = 0; i < 4; ++i)
#pragma unroll
    for (int j = 0; j < 4; ++j)
#pragma unroll
      for (int r = 0; r < 4; ++r) {
        int gr = m0 + wm + i * 16 + q * 4 + r;
        int gc = n0 + wn + j * 16 + mlo;
        float v = acc[i][j][r] + bias[gr];
        if (OUT_BF16)
          ((unsigned short*)Cb)[(long)blockIdx.z * strideC + (long)gr * N + gc] = f2bf(v);
        else
          ((float*)Cb)[(long)blockIdx.z * strideC + (long)gr * N + gc] = v;
      }
}

// ----------------------------------------------------------- toeplitz -------
// Counted-vmcnt pipelined rewrite (T3+T4+T5). The two causal passes (long
// tile t0L, short tile t0S) read the SAME B rows starting at s=0, so they are
// flattened into one 34-chunk sequence (nc0 = 2*(16-j) long + nc1 short).
// Quad-buffered Bs (LDS 69.8 KB -> 2 blocks/CU), stage depth 3 chunks,
// head-of-chunk s_waitcnt vmcnt(4)+lgkmcnt(0) + raw s_barrier; vmcnt never
// drains to 0 until the final chunk. A-fragment indexing / rotation /
// epilogue preserved verbatim from the verified version.
__global__ __launch_bounds__(256, 2) void toeplitz(const unsigned short* __restrict__ proj,
                                                   const unsigned short* __restrict__ Gr8,
                                                   unsigned short* __restrict__ mixedT) {
  __shared__ __align__(16) unsigned short Ls[8 * CAP];        // 36992 B
  __shared__ __align__(16) unsigned short Bs[4][2][64 * 32];  // 32768 B
  const int tid = threadIdx.x, lane = tid & 63, w = tid >> 6;
  const int j = blockIdx.x, h = blockIdx.y, bz = blockIdx.z;
  const int mlo = lane & 15, q = lane >> 4;
  const int wt = (w >> 1) * 64, we = (w & 1) * 32;
  const int t0L = (15 - j) * 128, t0S = j * 128;

  // ---- one-time LDS fill (issued first; retired before first chunk's wait)
  const int delta = (NT - 128) - t0L;
  const int MUSE = t0L + 256;
#pragma unroll 1
  for (int r = 0; r < 8; ++r) {
    int rr = (r + delta) & 7;
    int off8 = r + delta - rr;
    const unsigned short* src = Gr8 + (long)(h * 8 + rr) * GLEN + off8;
    unsigned short* dst = &Ls[r * CAP];
    for (int mc = tid; mc * 8 < MUSE; mc += 256) gload16(src + mc * 8, dst + mc * 8);
  }

  const int rA = (7 - mlo) & 7;
  const int eRow = tid >> 2, kCol = (tid & 3) * 8;
  const unsigned short* bsrc = proj + ((long)bz * ND + h * 64 + eRow) * NT + kCol;

  const int nc0 = 2 * (16 - j);  // long-pass chunks; nc0 + nc1 == 34 for all j
  const int NCT = 34;
  const unsigned short* lA0 = &Ls[rA * CAP + (127 - wt - mlo - rA) + q * 8];  // pass 0 (t0p=t0L)
  const unsigned short* lA1 = lA0 + (t0L - t0S);                              // pass 1 (t0p=t0S)

  auto stage = [&](int g) {  // 2 gloads per chunk (64 K)
    int c = (g < nc0) ? g : g - nc0;
    gload16(bsrc + c * 64, &Bs[g & 3][0][tid * 8]);
    gload16(bsrc + c * 64 + 32, &Bs[g & 3][1][tid * 8]);
  };

  stage(0);
  stage(1);
  stage(2);

  f32x4 acc[4][2];
  bf16x8 ap0 = {}, ap1 = {};
  const unsigned short* lA = lA0;

  auto sub = [&](int bf, int hh, int s) {
    bf16x8 a0 = __builtin_bit_cast(bf16x8, *(const us8*)(lA + s));
    bf16x8 a1 = __builtin_bit_cast(bf16x8, *(const us8*)(lA + s - 16));
    bf16x8 b0 = __builtin_bit_cast(bf16x8, *(const us8*)&Bs[bf][hh][(we + mlo) * 32 + q * 8]);
    bf16x8 b1 = __builtin_bit_cast(bf16x8, *(const us8*)&Bs[bf][hh][(we + 16 + mlo) * 32 + q * 8]);
    acc[0][0] = __builtin_amdgcn_mfma_f32_16x16x32_bf16(a0, b0, acc[0][0], 0, 0, 0);
    acc[0][1] = __builtin_amdgcn_mfma_f32_16x16x32_bf16(a0, b1, acc[0][1], 0, 0, 0);
    acc[1][0] = __builtin_amdgcn_mfma_f32_16x16x32_bf16(a1, b0, acc[1][0], 0, 0, 0);
    acc[1][1] = __builtin_amdgcn_mfma_f32_16x16x32_bf16(a1, b1, acc[1][1], 0, 0, 0);
    acc[2][0] = __builtin_amdgcn_mfma_f32_16x16x32_bf16(ap0, b0, acc[2][0], 0, 0, 0);
    acc[2][1] = __builtin_amdgcn_mfma_f32_16x16x32_bf16(ap0, b1, acc[2][1], 0, 0, 0);
    acc[3][0] = __builtin_amdgcn_mfma_f32_16x16x32_bf16(ap1, b0, acc[3][0], 0, 0, 0);
    acc[3][1] = __builtin_amdgcn_mfma_f32_16x16x32_bf16(ap1, b1, acc[3][1], 0, 0, 0);
    ap0 = a0;
    ap1 = a1;
  };

#pragma unroll 1
  for (int g = 0; g < NCT; ++g) {
    // in-flight after this wait: chunks g+1, g+2 (2 loads each); vmcnt retires
    // in issue order, so the one-time fill + chunk g are guaranteed landed.
    if (g + 2 < NCT)
      asm volatile("s_waitcnt vmcnt(4) lgkmcnt(0)" ::: "memory");
    else if (g + 1 < NCT)
      asm volatile("s_waitcnt vmcnt(2) lgkmcnt(0)" ::: "memory");
    else
      asm volatile("s_waitcnt vmcnt(0) lgkmcnt(0)" ::: "memory");
    __builtin_amdgcn_s_barrier();
    if (g + 3 < NCT) stage(g + 3);  // overwrites buf (g-1)&3: drained above

    const int pass = (g >= nc0) ? 1 : 0;
    const int c = pass ? g - nc0 : g;
    if (c == 0) {  // pass start: reset accumulator + A-rotation state
      lA = pass ? lA1 : lA0;
      ap0 = __builtin_bit_cast(bf16x8, *(const us8*)(lA - 32));
      ap1 = __builtin_bit_cast(bf16x8, *(const us8*)(lA - 48));
#pragma unroll
      for (int i = 0; i < 4; ++i)
#pragma unroll
        for (int jj = 0; jj < 2; ++jj) acc[i][jj] = f32x4{0.f, 0.f, 0.f, 0.f};
    }
    const int buf = g & 3;
    const int s0 = c * 64;
    __builtin_amdgcn_s_setprio(1);
    sub(buf, 0, s0);
    sub(buf, 1, s0 + 32);
    __builtin_amdgcn_s_setprio(0);

    if ((!pass && g == nc0 - 1) || g == NCT - 1) {  // pass epilogue
      const int t0p = pass ? t0S : t0L;
#pragma unroll
      for (int i = 0; i < 4; ++i)
#pragma unroll
        for (int jj = 0; jj < 2; ++jj)
#pragma unroll
          for (int rr = 0; rr < 4; ++rr) {
            int t = t0p + wt + i * 16 + q * 4 + rr;
            int e = we + jj * 16 + mlo;
            mixedT[((long)bz * NT + t) * ND + h * 64 + e] = f2bf(acc[i][jj][rr]);
          }
    }
  }
}

// ---------------------------------------------------------------------------
extern "C" void kernel_launch(void* const* d_in, const int* in_sizes, int n_in, void* d_out,
                              int out_size, void* d_ws, size_t ws_size, hipStream_t stream) {
  const float* x = (const float*)d_in[0];
  const float* Wp = (const float*)d_in[1];
  const float* bp = (const float*)d_in[2];
  const float* tw = (const float*)d_in[3];
  const float* Wo = (const float*)d_in[4];
  const float* bo = (const float*)d_in[5];
  float* out = (float*)d_out;

  char* ws = (char*)d_ws;
  unsigned short* xT = (unsigned short*)(ws);  // also mixedT after stage 2
  unsigned short* proj = (unsigned short*)(ws + (16ull << 20));
  unsigned short* WpB = (unsigned short*)(ws + (32ull << 20));
  unsigned short* WoB = (unsigned short*)(ws + (34ull << 20));
  unsigned short* Gr8 = (unsigned short*)(ws + (36ull << 20));

  prep_kernel<<<dim3(1024), 256, 0, stream>>>(Wp, Wo, tw, WpB, WoB, Gr8);
  transpose_cast<<<dim3(NT / 64, ND / 64, NB), 256, 0, stream>>>(x, xT);
  gemm_bt<true><<<dim3(8, 8, NB), 512, 0, stream>>>(WpB, xT, bp, proj, (long)NT * ND,
                                                    (long)ND * NT);
  toeplitz<<<dim3(8, NH, NB), 256, 0, stream>>>(proj, Gr8, xT);
  gemm_bt<false><<<dim3(8, 8, NB), 512, 0, stream>>>(WoB, xT, bo, out, (long)NT * ND,
                                                     (long)ND * NT);
}

// Round 3
// 155.355 us; speedup vs baseline: 1.0282x; 1.0282x over previous
//
#include <hip/hip_runtime.h>
#include <cstdint>

#define NB 4
#define ND 1024
#define NT 2048
#define NH 16
#define NE 64
#define GLEN 2240  // per-copy length of reversed global Toeplitz table (elements)
#define CAP 2312   // per-copy length of LDS table (elements)

typedef __bf16 bf16x8 __attribute__((ext_vector_type(8)));
typedef float f32x4 __attribute__((ext_vector_type(4)));
typedef unsigned short us8 __attribute__((ext_vector_type(8)));
typedef unsigned short us4 __attribute__((ext_vector_type(4)));

__device__ __forceinline__ unsigned short f2bf(float f) {
  unsigned u = __builtin_bit_cast(unsigned, f);
  return (unsigned short)((u + 0x7fffu + ((u >> 16) & 1u)) >> 16);  // RTNE
}

// async global->LDS, 16B per lane; LDS dest must be wave-uniform base + lane*16
__device__ __forceinline__ void gload16(const void* g, void* l) {
  __builtin_amdgcn_global_load_lds(
      (const __attribute__((address_space(1))) void*)(uintptr_t)g,
      (__attribute__((address_space(3))) void*)(uintptr_t)l, 16, 0, 0);
}

// ---------------------------------------------------------------- prep ------
__global__ void prep_kernel(const float* __restrict__ Wp, const float* __restrict__ Wo,
                            const float* __restrict__ tw,
                            unsigned short* __restrict__ WpB, unsigned short* __restrict__ WoB,
                            unsigned short* __restrict__ Gr8) {
  int idx = blockIdx.x * 256 + threadIdx.x;
  int stride = gridDim.x * 256;
  const int n4 = ND * ND / 4;
  for (int i = idx; i < n4; i += stride) {
    float4 v = ((const float4*)Wp)[i];
    us4 o = {f2bf(v.x), f2bf(v.y), f2bf(v.z), f2bf(v.w)};
    ((us4*)WpB)[i] = o;
  }
  for (int i = idx; i < n4; i += stride) {
    float4 v = ((const float4*)Wo)[i];
    us4 o = {f2bf(v.x), f2bf(v.y), f2bf(v.z), f2bf(v.w)};
    ((us4*)WoB)[i] = o;
  }
  for (int i = idx; i < NH * 8 * GLEN; i += stride) {
    int h = i / (8 * GLEN);
    int rem = i - h * 8 * GLEN;
    int r = rem / GLEN;
    int c = rem - r * GLEN;
    int src = c + r;
    Gr8[i] = (src <= NT - 1) ? f2bf(tw[h * NT + (NT - 1) - src]) : (unsigned short)0;
  }
}

// ------------------------------------------------------- transpose + cast ---
__global__ __launch_bounds__(256) void transpose_cast(const float* __restrict__ x,
                                                      unsigned short* __restrict__ xT) {
  __shared__ float tile[64][65];
  const int c = threadIdx.x & 15, r = threadIdx.x >> 4;
  const int t0 = blockIdx.x * 64, d0 = blockIdx.y * 64, b = blockIdx.z;
  const float* xb = x + (long)b * ND * NT;
#pragma unroll
  for (int k = 0; k < 4; ++k) {
    float4 v = *(const float4*)&xb[(long)(d0 + r + 16 * k) * NT + t0 + 4 * c];
    tile[r + 16 * k][4 * c + 0] = v.x;
    tile[r + 16 * k][4 * c + 1] = v.y;
    tile[r + 16 * k][4 * c + 2] = v.z;
    tile[r + 16 * k][4 * c + 3] = v.w;
  }
  __syncthreads();
  unsigned short* xTb = xT + (long)b * NT * ND;
#pragma unroll
  for (int k = 0; k < 4; ++k) {
    int t = r + 16 * k;
    us4 o = {f2bf(tile[4 * c + 0][t]), f2bf(tile[4 * c + 1][t]), f2bf(tile[4 * c + 2][t]),
             f2bf(tile[4 * c + 3][t])};
    *(us4*)&xTb[(long)(t0 + t) * ND + d0 + 4 * c] = o;
  }
}

// ----------------------------------------------------------- gemm_bt --------
// C[b][m][n] = sum_k A[m][k] * Bt[b][n][k] + bias[m]
// R3: 128x128 tile, 256 threads (4 waves of 64x64), BK=64 double-buffered
// (64 KiB LDS -> 2 blocks/CU, 8 waves/CU), grid 16x8x4 = 512 blocks = 2/CU.
// Counted prefetch with two barriers per K-tile:
//   [lgkm(0); bar1; stage(t+1); vmcnt(8); bar2; compute(t)]
// - bar1 proves all waves finished reading buf^1 (WAR fence for stage)
// - vmcnt(8): own tile-t loads landed (only t+1's 8 outstanding); never 0
//   until the final tile. XOR-swizzled source + swizzled ds_read (rule 21),
//   s_setprio around MFMA cluster.
template <bool OUT_BF16>
__global__ __launch_bounds__(256, 2) void gemm_bt(const unsigned short* __restrict__ A,
                                                  const unsigned short* __restrict__ Bt,
                                                  const float* __restrict__ bias,
                                                  void* __restrict__ Cb, long strideB,
                                                  long strideC) {
  const int N = 2048, K = 1024;
  __shared__ __align__(16) unsigned short As[2][128 * 64];  // 32 KiB
  __shared__ __align__(16) unsigned short Bs[2][128 * 64];  // 32 KiB
  const int tid = threadIdx.x;
  const int lane = tid & 63;
  const int wid = tid >> 6;  // 0..3
  const int wm = (wid & 1) * 64, wn = (wid >> 1) * 64;
  const int m0 = blockIdx.y * 128, n0 = blockIdx.x * 128;
  const unsigned short* Bb = Bt + (long)blockIdx.z * strideB;
  const int mlo = lane & 15, q = lane >> 4, m7 = mlo & 7;

  // staging map: chunk = p*256+tid (p=0..3), row = chunk>>3 (0..127),
  // blk = chunk&7; LDS dest linear (chunk*16B), global source block XOR'd.
  const unsigned short* aP[4];
  const unsigned short* bP[4];
  int dstc[4];
#pragma unroll
  for (int p = 0; p < 4; ++p) {
    int chunk = p * 256 + tid;
    int row = chunk >> 3, blk = chunk & 7;
    int sc = (blk ^ (row & 7)) * 8;  // inverse-swizzled source column (elems)
    aP[p] = A + (long)(m0 + row) * K + sc;
    bP[p] = Bb + (long)(n0 + row) * K + sc;
    dstc[p] = chunk * 8;
  }

  auto stage = [&](int buf, int t) {  // 8 gloads/thread
#pragma unroll
    for (int p = 0; p < 4; ++p) {
      gload16(aP[p] + t * 64, &As[buf][dstc[p]]);
      gload16(bP[p] + t * 64, &Bs[buf][dstc[p]]);
    }
  };

  f32x4 acc[4][4] = {};
  stage(0, 0);

#pragma unroll
  for (int t = 0; t < 16; ++t) {
    const int buf = t & 1;
    // bar1: all waves done reading buf^1 (their ds_reads drained via lgkm)
    asm volatile("s_waitcnt lgkmcnt(0)" ::: "memory");
    __builtin_amdgcn_s_barrier();
    if (t < 15) stage(buf ^ 1, t + 1);
    // own tile-t loads landed; at most 8 (tile t+1) outstanding
    if (t < 15)
      asm volatile("s_waitcnt vmcnt(8)" ::: "memory");
    else
      asm volatile("s_waitcnt vmcnt(0)" ::: "memory");
    __builtin_amdgcn_s_barrier();  // everyone's tile-t loads visible
#pragma unroll
    for (int ks = 0; ks < 2; ++ks) {
      bf16x8 av[4], bv[4];
      const int xb8 = ((4 * ks + q) ^ m7) * 8;
#pragma unroll
      for (int i = 0; i < 4; ++i) {
        av[i] = __builtin_bit_cast(bf16x8, *(const us8*)&As[buf][(wm + i * 16 + mlo) * 64 + xb8]);
        bv[i] = __builtin_bit_cast(bf16x8, *(const us8*)&Bs[buf][(wn + i * 16 + mlo) * 64 + xb8]);
      }
      __builtin_amdgcn_s_setprio(1);
#pragma unroll
      for (int i = 0; i < 4; ++i)
#pragma unroll
        for (int j = 0; j < 4; ++j)
          acc[i][j] = __builtin_amdgcn_mfma_f32_16x16x32_bf16(av[i], bv[j], acc[i][j], 0, 0, 0);
      __builtin_amdgcn_s_setprio(0);
    }
  }

  // epilogue: C/D layout col=lane&15, row=(lane>>4)*4+r
#pragma unroll
  for (int i = 0; i < 4; ++i)
#pragma unroll
    for (int j = 0; j < 4; ++j)
#pragma unroll
      for (int r = 0; r < 4; ++r) {
        int gr = m0 + wm + i * 16 + q * 4 + r;
        int gc = n0 + wn + j * 16 + mlo;
        float v = acc[i][j][r] + bias[gr];
        if (OUT_BF16)
          ((unsigned short*)Cb)[(long)blockIdx.z * strideC + (long)gr * N + gc] = f2bf(v);
        else
          ((float*)Cb)[(long)blockIdx.z * strideC + (long)gr * N + gc] = v;
      }
}

// ----------------------------------------------------------- toeplitz -------
// R2 pipelined structure kept. R3 change: grid is now (h, j, bz) so the 8
// j-blocks sharing the same (h,bz) proj rows land on ONE XCD (XCD = id%8 =
// h%8) -> proj reads become L2 hits instead of L3 round-trips (T1).
__global__ __launch_bounds__(256, 2) void toeplitz(const unsigned short* __restrict__ proj,
                                                   const unsigned short* __restrict__ Gr8,
                                                   unsigned short* __restrict__ mixedT) {
  __shared__ __align__(16) unsigned short Ls[8 * CAP];        // 36992 B
  __shared__ __align__(16) unsigned short Bs[4][2][64 * 32];  // 32768 B
  const int tid = threadIdx.x, lane = tid & 63, w = tid >> 6;
  const int j = blockIdx.y, h = blockIdx.x, bz = blockIdx.z;  // h-major for XCD L2 locality
  const int mlo = lane & 15, q = lane >> 4;
  const int wt = (w >> 1) * 64, we = (w & 1) * 32;
  const int t0L = (15 - j) * 128, t0S = j * 128;

  // ---- one-time LDS fill (issued first; retired before first chunk's wait)
  const int delta = (NT - 128) - t0L;
  const int MUSE = t0L + 256;
#pragma unroll 1
  for (int r = 0; r < 8; ++r) {
    int rr = (r + delta) & 7;
    int off8 = r + delta - rr;
    const unsigned short* src = Gr8 + (long)(h * 8 + rr) * GLEN + off8;
    unsigned short* dst = &Ls[r * CAP];
    for (int mc = tid; mc * 8 < MUSE; mc += 256) gload16(src + mc * 8, dst + mc * 8);
  }

  const int rA = (7 - mlo) & 7;
  const int eRow = tid >> 2, kCol = (tid & 3) * 8;
  const unsigned short* bsrc = proj + ((long)bz * ND + h * 64 + eRow) * NT + kCol;

  const int nc0 = 2 * (16 - j);  // long-pass chunks; nc0 + nc1 == 34 for all j
  const int NCT = 34;
  const unsigned short* lA0 = &Ls[rA * CAP + (127 - wt - mlo - rA) + q * 8];  // pass 0 (t0p=t0L)
  const unsigned short* lA1 = lA0 + (t0L - t0S);                              // pass 1 (t0p=t0S)

  auto stage = [&](int g) {  // 2 gloads per chunk (64 K)
    int c = (g < nc0) ? g : g - nc0;
    gload16(bsrc + c * 64, &Bs[g & 3][0][tid * 8]);
    gload16(bsrc + c * 64 + 32, &Bs[g & 3][1][tid * 8]);
  };

  stage(0);
  stage(1);
  stage(2);

  f32x4 acc[4][2];
  bf16x8 ap0 = {}, ap1 = {};
  const unsigned short* lA = lA0;

  auto sub = [&](int bf, int hh, int s) {
    bf16x8 a0 = __builtin_bit_cast(bf16x8, *(const us8*)(lA + s));
    bf16x8 a1 = __builtin_bit_cast(bf16x8, *(const us8*)(lA + s - 16));
    bf16x8 b0 = __builtin_bit_cast(bf16x8, *(const us8*)&Bs[bf][hh][(we + mlo) * 32 + q * 8]);
    bf16x8 b1 = __builtin_bit_cast(bf16x8, *(const us8*)&Bs[bf][hh][(we + 16 + mlo) * 32 + q * 8]);
    acc[0][0] = __builtin_amdgcn_mfma_f32_16x16x32_bf16(a0, b0, acc[0][0], 0, 0, 0);
    acc[0][1] = __builtin_amdgcn_mfma_f32_16x16x32_bf16(a0, b1, acc[0][1], 0, 0, 0);
    acc[1][0] = __builtin_amdgcn_mfma_f32_16x16x32_bf16(a1, b0, acc[1][0], 0, 0, 0);
    acc[1][1] = __builtin_amdgcn_mfma_f32_16x16x32_bf16(a1, b1, acc[1][1], 0, 0, 0);
    acc[2][0] = __builtin_amdgcn_mfma_f32_16x16x32_bf16(ap0, b0, acc[2][0], 0, 0, 0);
    acc[2][1] = __builtin_amdgcn_mfma_f32_16x16x32_bf16(ap0, b1, acc[2][1], 0, 0, 0);
    acc[3][0] = __builtin_amdgcn_mfma_f32_16x16x32_bf16(ap1, b0, acc[3][0], 0, 0, 0);
    acc[3][1] = __builtin_amdgcn_mfma_f32_16x16x32_bf16(ap1, b1, acc[3][1], 0, 0, 0);
    ap0 = a0;
    ap1 = a1;
  };

#pragma unroll 1
  for (int g = 0; g < NCT; ++g) {
    if (g + 2 < NCT)
      asm volatile("s_waitcnt vmcnt(4) lgkmcnt(0)" ::: "memory");
    else if (g + 1 < NCT)
      asm volatile("s_waitcnt vmcnt(2) lgkmcnt(0)" ::: "memory");
    else
      asm volatile("s_waitcnt vmcnt(0) lgkmcnt(0)" ::: "memory");
    __builtin_amdgcn_s_barrier();
    if (g + 3 < NCT) stage(g + 3);  // overwrites buf (g-1)&3: drained above

    const int pass = (g >= nc0) ? 1 : 0;
    const int c = pass ? g - nc0 : g;
    if (c == 0) {  // pass start: reset accumulator + A-rotation state
      lA = pass ? lA1 : lA0;
      ap0 = __builtin_bit_cast(bf16x8, *(const us8*)(lA - 32));
      ap1 = __builtin_bit_cast(bf16x8, *(const us8*)(lA - 48));
#pragma unroll
      for (int i = 0; i < 4; ++i)
#pragma unroll
        for (int jj = 0; jj < 2; ++jj) acc[i][jj] = f32x4{0.f, 0.f, 0.f, 0.f};
    }
    const int buf = g & 3;
    const int s0 = c * 64;
    __builtin_amdgcn_s_setprio(1);
    sub(buf, 0, s0);
    sub(buf, 1, s0 + 32);
    __builtin_amdgcn_s_setprio(0);

    if ((!pass && g == nc0 - 1) || g == NCT - 1) {  // pass epilogue
      const int t0p = pass ? t0S : t0L;
#pragma unroll
      for (int i = 0; i < 4; ++i)
#pragma unroll
        for (int jj = 0; jj < 2; ++jj)
#pragma unroll
          for (int rr = 0; rr < 4; ++rr) {
            int t = t0p + wt + i * 16 + q * 4 + rr;
            int e = we + jj * 16 + mlo;
            mixedT[((long)bz * NT + t) * ND + h * 64 + e] = f2bf(acc[i][jj][rr]);
          }
    }
  }
}

// ---------------------------------------------------------------------------
extern "C" void kernel_launch(void* const* d_in, const int* in_sizes, int n_in, void* d_out,
                              int out_size, void* d_ws, size_t ws_size, hipStream_t stream) {
  const float* x = (const float*)d_in[0];
  const float* Wp = (const float*)d_in[1];
  const float* bp = (const float*)d_in[2];
  const float* tw = (const float*)d_in[3];
  const float* Wo = (const float*)d_in[4];
  const float* bo = (const float*)d_in[5];
  float* out = (float*)d_out;

  char* ws = (char*)d_ws;
  unsigned short* xT = (unsigned short*)(ws);  // also mixedT after stage 2
  unsigned short* proj = (unsigned short*)(ws + (16ull << 20));
  unsigned short* WpB = (unsigned short*)(ws + (32ull << 20));
  unsigned short* WoB = (unsigned short*)(ws + (34ull << 20));
  unsigned short* Gr8 = (unsigned short*)(ws + (36ull << 20));

  prep_kernel<<<dim3(1024), 256, 0, stream>>>(Wp, Wo, tw, WpB, WoB, Gr8);
  transpose_cast<<<dim3(NT / 64, ND / 64, NB), 256, 0, stream>>>(x, xT);
  gemm_bt<true><<<dim3(16, 8, NB), 256, 0, stream>>>(WpB, xT, bp, proj, (long)NT * ND,
                                                     (long)ND * NT);
  toeplitz<<<dim3(NH, 8, NB), 256, 0, stream>>>(proj, Gr8, xT);
  gemm_bt<false><<<dim3(16, 8, NB), 256, 0, stream>>>(WoB, xT, bo, out, (long)NT * ND,
                                                      (long)ND * NT);
}